// Round 7
// baseline (638.639 us; speedup 1.0000x reference)
//
#include <hip/hip_runtime.h>
#include <math.h>

#define IMG_H 512
#define IMG_W 512
#define NPLANE 48                 // 16 batches * 3 channels
#define NXT 8                     // 512/64 column tiles
#define NSEG 8                    // 512/64 row segments
#define NTASK (NPLANE*NXT*NSEG)   // 3072 waves
#define NPIX 12582912.0           // 16*3*512*512

struct GaussW { float w[11]; };

__global__ void ssim_zero_kernel(double* acc) {
    if (threadIdx.x == 0) acc[0] = 0.0;
}

// One wave owns a 64-col x 64-row tile of one (b,c) plane.
// NO private arrays anywhere: SROA runs before loop-unrolling, so even
// pragma-unrolled variable indices leave allocas in scratch (round-5
// evidence: WRITE_SIZE 557 MB, VGPR stuck at 84). Every ring slot / tap
// column / tap weight is a NAMED SCALAR via token-pasting macros.
__global__ __launch_bounds__(256, 3)
void ssim_main_kernel(const float* __restrict__ pred,
                      const float* __restrict__ targ,
                      double* __restrict__ acc,
                      GaussW gw) {
    const int wid  = (blockIdx.x << 2) + (threadIdx.x >> 6);
    const int lane = threadIdx.x & 63;
    const int xt   = wid & 7;          // adjacent waves share x-halo in L1/L2
    const int yseg = (wid >> 3) & 7;
    const int pl   = wid >> 6;
    const int x    = (xt << 6) + lane;
    const int y0   = yseg << 6;

    const float* __restrict__ pb = pred + (size_t)pl * (IMG_H * IMG_W);
    const float* __restrict__ tb = targ + (size_t)pl * (IMG_H * IMG_W);

    // Per-lane clamped tap columns + masked weights, as named scalars.
    // Out-of-image taps: weight 0, address clamped in-range (value ignored).
#define DECL_TAP(K)                                                          \
    const int   cq##K = x + (K) - 5;                                         \
    const int   cx##K = cq##K < 0 ? 0 : (cq##K > IMG_W - 1 ? IMG_W - 1 : cq##K); \
    const float wv##K = ((unsigned)cq##K < (unsigned)IMG_W) ? gw.w[K] : 0.f;
    DECL_TAP(0) DECL_TAP(1) DECL_TAP(2) DECL_TAP(3) DECL_TAP(4) DECL_TAP(5)
    DECL_TAP(6) DECL_TAP(7) DECL_TAP(8) DECL_TAP(9) DECL_TAP(10)
#undef DECL_TAP

    // Register ring: 11 rows x 5 fields of hconv results, named scalars.
#define DECL_RING(F) float F##0, F##1, F##2, F##3, F##4, F##5, F##6, F##7, F##8, F##9, F##10;
    DECL_RING(rmx) DECL_RING(rmy) DECL_RING(rxx) DECL_RING(ryy) DECL_RING(rxy)
#undef DECL_RING

// One horizontal tap K (literal): accumulate 5 field products.
#define HTAP(K) {                                                            \
    const float p  = pr[cx##K];                                              \
    const float t  = tr[cx##K];                                              \
    const float wp = wv##K * p;                                              \
    const float wt = wv##K * t;                                              \
    amx += wp; amy += wt;                                                    \
    axx = fmaf(wp, p, axx);                                                  \
    ayy = fmaf(wt, t, ayy);                                                  \
    axy = fmaf(wp, t, axy); }

// Horizontal 11-tap conv of row YV into ring slot S (literal token).
#define HROW(YV, S) do {                                                     \
    const int y_ = (YV);                                                     \
    float amx = 0.f, amy = 0.f, axx = 0.f, ayy = 0.f, axy = 0.f;             \
    if ((unsigned)y_ < (unsigned)IMG_H) {  /* wave-uniform branch */         \
        const float* __restrict__ pr = pb + y_ * IMG_W;                      \
        const float* __restrict__ tr = tb + y_ * IMG_W;                      \
        HTAP(0) HTAP(1) HTAP(2) HTAP(3) HTAP(4) HTAP(5)                      \
        HTAP(6) HTAP(7) HTAP(8) HTAP(9) HTAP(10)                             \
    }                                                                        \
    rmx##S = amx; rmy##S = amy;                                              \
    rxx##S = axx; ryy##S = ayy; rxy##S = axy;                                \
} while (0)

    // Prologue: slots 0..9 = hconv of rows y0-5 .. y0+4 (slot s = row y0-5+s).
    HROW(y0 - 5, 0); HROW(y0 - 4, 1); HROW(y0 - 3, 2); HROW(y0 - 2, 3);
    HROW(y0 - 1, 4); HROW(y0 + 0, 5); HROW(y0 + 1, 6); HROW(y0 + 2, 7);
    HROW(y0 + 3, 8); HROW(y0 + 4, 9);

    const float C1 = 0.0001f;   // 0.01^2
    const float C2 = 0.0009f;   // 0.03^2
    float sum = 0.f;

// Vertical tap: slot S (literal) at phase JJ (literal). Slot s holds row
// j-5+k with k=(s-JJ) mod 11, so weight index = (S+11-JJ)%11 (constexpr).
#define VTAP(JJ, S) {                                                        \
    const float wk = gw.w[((S) + 11 - (JJ)) % 11];                           \
    mx = fmaf(wk, rmx##S, mx);                                               \
    my = fmaf(wk, rmy##S, my);                                               \
    xx = fmaf(wk, rxx##S, xx);                                               \
    yy = fmaf(wk, ryy##S, yy);                                               \
    xy = fmaf(wk, rxy##S, xy); }

// Output row at phase JJ; SNEW = (JJ+10)%11 passed as a literal token.
#define PHASE(JJ, SNEW) do {                                                 \
    const int j_ = c * 11 + (JJ);                                            \
    HROW(y0 + 5 + j_, SNEW);                                                 \
    float mx = 0.f, my = 0.f, xx = 0.f, yy = 0.f, xy = 0.f;                  \
    VTAP(JJ, 0) VTAP(JJ, 1) VTAP(JJ, 2) VTAP(JJ, 3) VTAP(JJ, 4) VTAP(JJ, 5)  \
    VTAP(JJ, 6) VTAP(JJ, 7) VTAP(JJ, 8) VTAP(JJ, 9) VTAP(JJ, 10)             \
    const float mx2  = mx * mx, my2 = my * my;                               \
    const float mxy2 = 2.f * (mx * my);                                      \
    const float sx   = xx - mx2, sy = yy - my2;                              \
    const float sxy2 = 2.f * xy - mxy2;                                      \
    const float num  = (mxy2 + C1) * (sxy2 + C2);                            \
    const float den  = (mx2 + my2 + C1) * (sx + sy + C2);                    \
    sum += (j_ < 64) ? __fdividef(num, den) : 0.f;                           \
} while (0)

    // 66 steps = 6 chunks x 11 literal phases; last 2 steps masked (j>=64).
#pragma unroll 1
    for (int c = 0; c < 6; ++c) {
        PHASE(0, 10); PHASE(1, 0); PHASE(2, 1); PHASE(3, 2); PHASE(4, 3);
        PHASE(5, 4);  PHASE(6, 5); PHASE(7, 6); PHASE(8, 7); PHASE(9, 8);
        PHASE(10, 9);
    }

#undef PHASE
#undef VTAP
#undef HROW
#undef HTAP

    // Wave tree-reduce, one f64 atomic per wave (3072 total).
#pragma unroll
    for (int m = 32; m > 0; m >>= 1) sum += __shfl_xor(sum, m);
    if (lane == 0) atomicAdd(acc, (double)sum);
}

__global__ void ssim_fin_kernel(const double* __restrict__ acc, float* __restrict__ out) {
    out[0] = (float)(1.0 - acc[0] / NPIX);
}

extern "C" void kernel_launch(void* const* d_in, const int* in_sizes, int n_in,
                              void* d_out, int out_size, void* d_ws, size_t ws_size,
                              hipStream_t stream) {
    const float* pred = (const float*)d_in[0];
    const float* targ = (const float*)d_in[1];
    float* out  = (float*)d_out;
    double* acc = (double*)d_ws;

    // Gaussian window (matches reference: exp(-(i-5)^2 / (2*1.5^2)), normalized)
    GaussW gw;
    double g[11], s = 0.0;
    for (int i = 0; i < 11; ++i) { double d = i - 5; g[i] = exp(-(d * d) / 4.5); s += g[i]; }
    for (int i = 0; i < 11; ++i) gw.w[i] = (float)(g[i] / s);

    ssim_zero_kernel<<<1, 64, 0, stream>>>(acc);
    ssim_main_kernel<<<NTASK / 4, 256, 0, stream>>>(pred, targ, acc, gw);
    ssim_fin_kernel<<<1, 1, 0, stream>>>(acc, out);
}

// Round 8
// 262.147 us; speedup vs baseline: 2.4362x; 2.4362x over previous
//
#include <hip/hip_runtime.h>
#include <math.h>

#define IMG_H 512
#define IMG_W 512
#define NPLANE 48                 // 16 batches * 3 channels
#define NXT 8                     // 512/64 column tiles
#define NSEG 8                    // 512/64 row segments
#define NTASK (NPLANE*NXT*NSEG)   // 3072 waves
#define NPIX 12582912.0           // 16*3*512*512

__global__ void ssim_zero_kernel(double* acc) {
    if (threadIdx.x == 0) acc[0] = 0.0;
}

// One wave owns a 64-col x 64-row tile of one (b,c) plane.
// Round-7 evidence: named scalars alone didn't stop scratch traffic
// (WRITE 1.07 GB, VGPR pinned at 84). Revised cause: VGPR cap from
// __launch_bounds__ second arg + pre-RA scheduler hoisting ~240 loads
// across flat phase bodies -> allocator spill. Fix: (a) no VGPR cap
// (launch_bounds(256) only), (b) sched_barrier(0) fences between phases
// to keep load live-ranges phase-local, (c) no struct arg (6 scalar
// weight args; symmetric taps are bit-identical).
__global__ __launch_bounds__(256)
void ssim_main_kernel(const float* __restrict__ pred,
                      const float* __restrict__ targ,
                      double* __restrict__ acc,
                      float w0, float w1, float w2,
                      float w3, float w4, float w5) {
    const int wid  = (blockIdx.x << 2) + (threadIdx.x >> 6);
    const int lane = threadIdx.x & 63;
    const int xt   = wid & 7;          // adjacent waves share x-halo in L1/L2
    const int yseg = (wid >> 3) & 7;
    const int pl   = wid >> 6;
    const int x    = (xt << 6) + lane;
    const int y0   = yseg << 6;

    const float* __restrict__ pb = pred + (size_t)pl * (IMG_H * IMG_W);
    const float* __restrict__ tb = targ + (size_t)pl * (IMG_H * IMG_W);

// Symmetric Gaussian weight by constant index (folds at compile time).
#define WSYM(M) ((M)==0||(M)==10 ? w0 : (M)==1||(M)==9 ? w1 :               \
                 (M)==2||(M)==8  ? w2 : (M)==3||(M)==7 ? w3 :               \
                 (M)==4||(M)==6  ? w4 : w5)

    // Per-lane clamped tap columns + masked weights, as named scalars.
    // Out-of-image taps: weight 0, address clamped in-range (value ignored).
#define DECL_TAP(K)                                                          \
    const int   cq##K = x + (K) - 5;                                         \
    const int   cx##K = cq##K < 0 ? 0 : (cq##K > IMG_W - 1 ? IMG_W - 1 : cq##K); \
    const float wv##K = ((unsigned)cq##K < (unsigned)IMG_W) ? WSYM(K) : 0.f;
    DECL_TAP(0) DECL_TAP(1) DECL_TAP(2) DECL_TAP(3) DECL_TAP(4) DECL_TAP(5)
    DECL_TAP(6) DECL_TAP(7) DECL_TAP(8) DECL_TAP(9) DECL_TAP(10)
#undef DECL_TAP

    // Register ring: 11 rows x 5 fields of hconv results, named scalars.
#define DECL_RING(F) float F##0, F##1, F##2, F##3, F##4, F##5, F##6, F##7, F##8, F##9, F##10;
    DECL_RING(rmx) DECL_RING(rmy) DECL_RING(rxx) DECL_RING(ryy) DECL_RING(rxy)
#undef DECL_RING

// One horizontal tap K (literal): accumulate 5 field products.
#define HTAP(K) {                                                            \
    const float p  = pr[cx##K];                                              \
    const float t  = tr[cx##K];                                              \
    const float wp = wv##K * p;                                              \
    const float wt = wv##K * t;                                              \
    amx += wp; amy += wt;                                                    \
    axx = fmaf(wp, p, axx);                                                  \
    ayy = fmaf(wt, t, ayy);                                                  \
    axy = fmaf(wp, t, axy); }

// Horizontal 11-tap conv of row YV into ring slot S (literal token).
#define HROW(YV, S) do {                                                     \
    const int y_ = (YV);                                                     \
    float amx = 0.f, amy = 0.f, axx = 0.f, ayy = 0.f, axy = 0.f;             \
    if ((unsigned)y_ < (unsigned)IMG_H) {  /* wave-uniform branch */         \
        const float* __restrict__ pr = pb + y_ * IMG_W;                      \
        const float* __restrict__ tr = tb + y_ * IMG_W;                      \
        HTAP(0) HTAP(1) HTAP(2) HTAP(3) HTAP(4) HTAP(5)                      \
        HTAP(6) HTAP(7) HTAP(8) HTAP(9) HTAP(10)                             \
    }                                                                        \
    rmx##S = amx; rmy##S = amy;                                              \
    rxx##S = axx; ryy##S = ayy; rxy##S = axy;                                \
} while (0)

    // Prologue: slots 0..9 = hconv of rows y0-5 .. y0+4 (slot s = row y0-5+s).
    // sched_barrier between rows: keep each row's 22 loads phase-local.
    HROW(y0 - 5, 0); __builtin_amdgcn_sched_barrier(0);
    HROW(y0 - 4, 1); __builtin_amdgcn_sched_barrier(0);
    HROW(y0 - 3, 2); __builtin_amdgcn_sched_barrier(0);
    HROW(y0 - 2, 3); __builtin_amdgcn_sched_barrier(0);
    HROW(y0 - 1, 4); __builtin_amdgcn_sched_barrier(0);
    HROW(y0 + 0, 5); __builtin_amdgcn_sched_barrier(0);
    HROW(y0 + 1, 6); __builtin_amdgcn_sched_barrier(0);
    HROW(y0 + 2, 7); __builtin_amdgcn_sched_barrier(0);
    HROW(y0 + 3, 8); __builtin_amdgcn_sched_barrier(0);
    HROW(y0 + 4, 9); __builtin_amdgcn_sched_barrier(0);

    const float C1 = 0.0001f;   // 0.01^2
    const float C2 = 0.0009f;   // 0.03^2
    float sum = 0.f;

// Vertical tap: slot S (literal) at phase JJ (literal). Slot s holds row
// j-5+k with k=(s-JJ) mod 11, so weight index = (S+11-JJ)%11 (constexpr).
#define VTAP(JJ, S) {                                                        \
    const float wk = WSYM(((S) + 11 - (JJ)) % 11);                           \
    mx = fmaf(wk, rmx##S, mx);                                               \
    my = fmaf(wk, rmy##S, my);                                               \
    xx = fmaf(wk, rxx##S, xx);                                               \
    yy = fmaf(wk, ryy##S, yy);                                               \
    xy = fmaf(wk, rxy##S, xy); }

// Output row at phase JJ; SNEW = (JJ+10)%11 passed as a literal token.
#define PHASE(JJ, SNEW) do {                                                 \
    const int j_ = c * 11 + (JJ);                                            \
    HROW(y0 + 5 + j_, SNEW);                                                 \
    float mx = 0.f, my = 0.f, xx = 0.f, yy = 0.f, xy = 0.f;                  \
    VTAP(JJ, 0) VTAP(JJ, 1) VTAP(JJ, 2) VTAP(JJ, 3) VTAP(JJ, 4) VTAP(JJ, 5)  \
    VTAP(JJ, 6) VTAP(JJ, 7) VTAP(JJ, 8) VTAP(JJ, 9) VTAP(JJ, 10)             \
    const float mx2  = mx * mx, my2 = my * my;                               \
    const float mxy2 = 2.f * (mx * my);                                      \
    const float sx   = xx - mx2, sy = yy - my2;                              \
    const float sxy2 = 2.f * xy - mxy2;                                      \
    const float num  = (mxy2 + C1) * (sxy2 + C2);                            \
    const float den  = (mx2 + my2 + C1) * (sx + sy + C2);                    \
    sum += (j_ < 64) ? __fdividef(num, den) : 0.f;                           \
    __builtin_amdgcn_sched_barrier(0);                                       \
} while (0)

    // 66 steps = 6 chunks x 11 literal phases; last 2 steps masked (j>=64).
#pragma unroll 1
    for (int c = 0; c < 6; ++c) {
        PHASE(0, 10); PHASE(1, 0); PHASE(2, 1); PHASE(3, 2); PHASE(4, 3);
        PHASE(5, 4);  PHASE(6, 5); PHASE(7, 6); PHASE(8, 7); PHASE(9, 8);
        PHASE(10, 9);
    }

#undef PHASE
#undef VTAP
#undef HROW
#undef HTAP
#undef WSYM

    // Wave tree-reduce, one f64 atomic per wave (3072 total).
#pragma unroll
    for (int m = 32; m > 0; m >>= 1) sum += __shfl_xor(sum, m);
    if (lane == 0) atomicAdd(acc, (double)sum);
}

__global__ void ssim_fin_kernel(const double* __restrict__ acc, float* __restrict__ out) {
    out[0] = (float)(1.0 - acc[0] / NPIX);
}

extern "C" void kernel_launch(void* const* d_in, const int* in_sizes, int n_in,
                              void* d_out, int out_size, void* d_ws, size_t ws_size,
                              hipStream_t stream) {
    const float* pred = (const float*)d_in[0];
    const float* targ = (const float*)d_in[1];
    float* out  = (float*)d_out;
    double* acc = (double*)d_ws;

    // Gaussian window (matches reference: exp(-(i-5)^2 / (2*1.5^2)), normalized).
    // Symmetric: w[k]==w[10-k] bit-exactly, so pass only 6 uniques.
    double g[11], s = 0.0;
    for (int i = 0; i < 11; ++i) { double d = i - 5; g[i] = exp(-(d * d) / 4.5); s += g[i]; }
    float w[6];
    for (int i = 0; i < 6; ++i) w[i] = (float)(g[i] / s);

    ssim_zero_kernel<<<1, 64, 0, stream>>>(acc);
    ssim_main_kernel<<<NTASK / 4, 256, 0, stream>>>(pred, targ, acc,
                                                    w[0], w[1], w[2], w[3], w[4], w[5]);
    ssim_fin_kernel<<<1, 1, 0, stream>>>(acc, out);
}

// Round 9
// 255.493 us; speedup vs baseline: 2.4996x; 1.0260x over previous
//
#include <hip/hip_runtime.h>
#include <math.h>

#define IMG_H 512
#define IMG_W 512
#define NPLANE 48                 // 16 batches * 3 channels
#define NTASK (NPLANE*8*8)        // 3072 waves
#define NPIX 12582912.0           // 16*3*512*512

__global__ void ssim_zero_kernel(double* acc) {
    if (threadIdx.x == 0) acc[0] = 0.0;
}

// Force a wave-uniform value into SGPRs so loads use s[base]+v_off form.
__device__ __forceinline__ const float* uniform_ptr(const float* p) {
    uint64_t u = (uint64_t)(uintptr_t)p;
    uint32_t lo = __builtin_amdgcn_readfirstlane((uint32_t)u);
    uint32_t hi = __builtin_amdgcn_readfirstlane((uint32_t)(u >> 32));
    return (const float*)(uintptr_t)(((uint64_t)hi << 32) | (uint64_t)lo);
}

// One wave = one 64-col x 64-row tile of one (b,c) plane.
// Round-8 fixed the scratch spill (VGPR 152, WRITE 96KB). Remaining 8x gap
// vs the 27us VALU floor = un-hidden load latency: per-phase vmcnt(0) drain,
// no prefetch, 3 waves/SIMD. This round: A/B pixel double-buffer (issue row
// i+1 loads before computing row i -> counted vmcnt(22) waits), SGPR row
// bases via readfirstlane, sched_barrier(0x7) so VMEM stays phase-local
// while ALU can flow. Chunks of 22 phases (lcm of ring=11, buffers=2) keep
// every index a literal -> all register-resident.
__global__ __launch_bounds__(256)
void ssim_main_kernel(const float* __restrict__ pred,
                      const float* __restrict__ targ,
                      double* __restrict__ acc,
                      float w0, float w1, float w2,
                      float w3, float w4, float w5) {
    const int wid  = (blockIdx.x << 2) + (threadIdx.x >> 6);
    const int lane = threadIdx.x & 63;
    const int xt   = wid & 7;          // adjacent waves share x-halo in L1/L2
    const int yseg = (wid >> 3) & 7;
    const int pl   = wid >> 6;
    const int x    = (xt << 6) + lane;
    const int y0u  = __builtin_amdgcn_readfirstlane(yseg << 6);  // uniform

    const float* pbu = uniform_ptr(pred + (size_t)pl * (IMG_H * IMG_W));
    const float* tbu = uniform_ptr(targ + (size_t)pl * (IMG_H * IMG_W));

// Symmetric Gaussian weight by constant index (folds at compile time).
#define WSYM(M) ((M)==0||(M)==10 ? w0 : (M)==1||(M)==9 ? w1 :               \
                 (M)==2||(M)==8  ? w2 : (M)==3||(M)==7 ? w3 :               \
                 (M)==4||(M)==6  ? w4 : w5)

    // Per-lane clamped tap columns (unsigned -> zext addressing) + masked
    // weights. Out-of-image taps: weight 0, address clamped (value ignored).
#define DECL_TAP(K)                                                          \
    const int      cq##K = x + (K) - 5;                                      \
    const unsigned co##K = (unsigned)(cq##K < 0 ? 0 :                        \
                           (cq##K > IMG_W - 1 ? IMG_W - 1 : cq##K));         \
    const float    wv##K = ((unsigned)cq##K < (unsigned)IMG_W) ? WSYM(K) : 0.f;
    DECL_TAP(0) DECL_TAP(1) DECL_TAP(2) DECL_TAP(3) DECL_TAP(4) DECL_TAP(5)
    DECL_TAP(6) DECL_TAP(7) DECL_TAP(8) DECL_TAP(9) DECL_TAP(10)
#undef DECL_TAP

    // Pixel double-buffers (A/B), 22 floats each.
#define DECL_BUF(B) float B##p0,B##p1,B##p2,B##p3,B##p4,B##p5,B##p6,B##p7,  \
                          B##p8,B##p9,B##p10,                               \
                          B##t0,B##t1,B##t2,B##t3,B##t4,B##t5,B##t6,B##t7,  \
                          B##t8,B##t9,B##t10;
    DECL_BUF(A) DECL_BUF(B)
#undef DECL_BUF

    // Ring: 11 rows x 5 fields of hconv results (zero-init: early phases
    // read not-yet-written slots; results are select-discarded).
#define DECL_RING(F) float F##0=0.f,F##1=0.f,F##2=0.f,F##3=0.f,F##4=0.f,     \
                           F##5=0.f,F##6=0.f,F##7=0.f,F##8=0.f,F##9=0.f,F##10=0.f;
    DECL_RING(rmx) DECL_RING(rmy) DECL_RING(rxx) DECL_RING(ryy) DECL_RING(rxy)
#undef DECL_RING

#define LR1(BUF, K) BUF##p##K = rp_[co##K]; BUF##t##K = rt_[co##K];
// Issue 22 loads of row (y0-5+IDX), clamped, into BUF. Base is SGPR-uniform.
#define LOADROW(BUF, IDX) do {                                               \
    const int yq_ = y0u - 5 + (IDX);                                         \
    const int yc_ = yq_ < 0 ? 0 : (yq_ > IMG_H - 1 ? IMG_H - 1 : yq_);       \
    const float* rp_ = pbu + yc_ * IMG_W;                                    \
    const float* rt_ = tbu + yc_ * IMG_W;                                    \
    LR1(BUF,0) LR1(BUF,1) LR1(BUF,2) LR1(BUF,3) LR1(BUF,4) LR1(BUF,5)        \
    LR1(BUF,6) LR1(BUF,7) LR1(BUF,8) LR1(BUF,9) LR1(BUF,10)                  \
} while (0)

#define HT(BUF, K) {                                                         \
    const float p_ = BUF##p##K, t_ = BUF##t##K;                              \
    const float wp_ = wv##K * p_, wt_ = wv##K * t_;                          \
    amx += wp_; amy += wt_;                                                  \
    axx = fmaf(wp_, p_, axx);                                                \
    ayy = fmaf(wt_, t_, ayy);                                                \
    axy = fmaf(wp_, t_, axy); }

#define VT(Q11, S) {                                                         \
    const float wk_ = WSYM(((S) + 10 - (Q11)) % 11);                         \
    mx = fmaf(wk_, rmx##S, mx);                                              \
    my = fmaf(wk_, rmy##S, my);                                              \
    xx = fmaf(wk_, rxx##S, xx);                                              \
    yy = fmaf(wk_, ryy##S, yy);                                              \
    xy = fmaf(wk_, rxy##S, xy); }

    const float C1 = 0.0001f;   // 0.01^2
    const float C2 = 0.0009f;   // 0.03^2
    float sum = 0.f;

// One phase: issue row IDXE+1 into BN; hconv row IDXE from BC into ring slot
// Q11 (zeroed if row out of image); vconv+SSIM for output row IDXE-10.
#define PHASE(IDXE, Q11, BC, BN) do {                                        \
    LOADROW(BN, (IDXE) + 1);                                                 \
    {                                                                        \
        float amx=0.f, amy=0.f, axx=0.f, ayy=0.f, axy=0.f;                   \
        HT(BC,0) HT(BC,1) HT(BC,2) HT(BC,3) HT(BC,4) HT(BC,5)                \
        HT(BC,6) HT(BC,7) HT(BC,8) HT(BC,9) HT(BC,10)                        \
        const bool vld_ = (unsigned)(y0u - 5 + (IDXE)) < (unsigned)IMG_H;    \
        rmx##Q11 = vld_ ? amx : 0.f;  rmy##Q11 = vld_ ? amy : 0.f;           \
        rxx##Q11 = vld_ ? axx : 0.f;  ryy##Q11 = vld_ ? ayy : 0.f;           \
        rxy##Q11 = vld_ ? axy : 0.f;                                         \
    }                                                                        \
    {                                                                        \
        float mx=0.f, my=0.f, xx=0.f, yy=0.f, xy=0.f;                        \
        VT(Q11,0) VT(Q11,1) VT(Q11,2) VT(Q11,3) VT(Q11,4) VT(Q11,5)          \
        VT(Q11,6) VT(Q11,7) VT(Q11,8) VT(Q11,9) VT(Q11,10)                   \
        const float mx2  = mx * mx, my2 = my * my;                           \
        const float mxy2 = 2.f * (mx * my);                                  \
        const float sx   = xx - mx2, sy = yy - my2;                          \
        const float sxy2 = 2.f * xy - mxy2;                                  \
        const float num  = (mxy2 + C1) * (sxy2 + C2);                        \
        const float den  = (mx2 + my2 + C1) * (sx + sy + C2);                \
        const int   j_   = (IDXE) - 10;                                      \
        sum += (j_ >= 0) ? __fdividef(num, den) : 0.f;                       \
    }                                                                        \
    __builtin_amdgcn_sched_barrier(0x7); /* ALU may cross; VMEM pinned */    \
} while (0)

    // Prologue: row 0 (y0-5) into A.
    LOADROW(A, 0);

    // 74 rows total (outputs j=0..63 at i=10..73): 3 chunks x 22 + 8 tail.
    // i = cc*22 + q; ring slot = q%11; buffer parity = q&1 (22 even => both
    // mappings are chunk-invariant, all indices literal).
#pragma unroll 1
    for (int cc = 0; cc < 3; ++cc) {
        const int ib = cc * 22;
        PHASE(ib+0 ,0 ,A,B); PHASE(ib+1 ,1 ,B,A); PHASE(ib+2 ,2 ,A,B);
        PHASE(ib+3 ,3 ,B,A); PHASE(ib+4 ,4 ,A,B); PHASE(ib+5 ,5 ,B,A);
        PHASE(ib+6 ,6 ,A,B); PHASE(ib+7 ,7 ,B,A); PHASE(ib+8 ,8 ,A,B);
        PHASE(ib+9 ,9 ,B,A); PHASE(ib+10,10,A,B); PHASE(ib+11,0 ,B,A);
        PHASE(ib+12,1 ,A,B); PHASE(ib+13,2 ,B,A); PHASE(ib+14,3 ,A,B);
        PHASE(ib+15,4 ,B,A); PHASE(ib+16,5 ,A,B); PHASE(ib+17,6 ,B,A);
        PHASE(ib+18,7 ,A,B); PHASE(ib+19,8 ,B,A); PHASE(ib+20,9 ,A,B);
        PHASE(ib+21,10,B,A);
    }
    // Tail: i = 66..73 (66%11==0, 66 even -> same literal mappings).
    PHASE(66,0,A,B); PHASE(67,1,B,A); PHASE(68,2,A,B); PHASE(69,3,B,A);
    PHASE(70,4,A,B); PHASE(71,5,B,A); PHASE(72,6,A,B); PHASE(73,7,B,A);

#undef PHASE
#undef VT
#undef HT
#undef LOADROW
#undef LR1
#undef WSYM

    // Wave tree-reduce, one f64 atomic per wave (3072 total).
#pragma unroll
    for (int m = 32; m > 0; m >>= 1) sum += __shfl_xor(sum, m);
    if (lane == 0) atomicAdd(acc, (double)sum);
}

__global__ void ssim_fin_kernel(const double* __restrict__ acc, float* __restrict__ out) {
    out[0] = (float)(1.0 - acc[0] / NPIX);
}

extern "C" void kernel_launch(void* const* d_in, const int* in_sizes, int n_in,
                              void* d_out, int out_size, void* d_ws, size_t ws_size,
                              hipStream_t stream) {
    const float* pred = (const float*)d_in[0];
    const float* targ = (const float*)d_in[1];
    float* out  = (float*)d_out;
    double* acc = (double*)d_ws;

    // Gaussian window (matches reference: exp(-(i-5)^2 / (2*1.5^2)), normalized).
    // Symmetric: w[k]==w[10-k] bit-exactly, so pass only 6 uniques.
    double g[11], s = 0.0;
    for (int i = 0; i < 11; ++i) { double d = i - 5; g[i] = exp(-(d * d) / 4.5); s += g[i]; }
    float w[6];
    for (int i = 0; i < 6; ++i) w[i] = (float)(g[i] / s);

    ssim_zero_kernel<<<1, 64, 0, stream>>>(acc);
    ssim_main_kernel<<<NTASK / 4, 256, 0, stream>>>(pred, targ, acc,
                                                    w[0], w[1], w[2], w[3], w[4], w[5]);
    ssim_fin_kernel<<<1, 1, 0, stream>>>(acc, out);
}

// Round 11
// 213.514 us; speedup vs baseline: 2.9911x; 1.1966x over previous
//
#include <hip/hip_runtime.h>
#include <math.h>

#define IMG_H 512
#define IMG_W 512
#define NPLANE 48                 // 16 batches * 3 channels
#define NTASK (NPLANE*8*8)        // 3072 waves
#define NPIX 12582912.0           // 16*3*512*512

__global__ void ssim_zero_kernel(double* acc) {
    if (threadIdx.x == 0) acc[0] = 0.0;
}

// Force a wave-uniform value into SGPRs so loads use s[base]+v_off form.
__device__ __forceinline__ const float* uniform_ptr(const float* p) {
    uint64_t u = (uint64_t)(uintptr_t)p;
    uint32_t lo = __builtin_amdgcn_readfirstlane((uint32_t)u);
    uint32_t hi = __builtin_amdgcn_readfirstlane((uint32_t)(u >> 32));
    return (const float*)(uintptr_t)(((uint64_t)hi << 32) | (uint64_t)lo);
}

// One wave = one 64-col x 64-row tile of one (b,c) plane.
// Round-9 evidence: spill fixed (WRITE 96KB) and prefetch restructure gave
// only 216->172us with VALU 33% and HBM 5% -> front-end (I-cache) bound:
// 74 straight-line phases = ~120KB code, 35KB loop body >> 32KB I$.
// This round: SHIFT-QUEUE ring (12 literal slots, shift-by-2 per iter)
// so the main loop is 2 phases / ~2.9KB and stays I$-resident.
__global__ __launch_bounds__(256)
void ssim_main_kernel(const float* __restrict__ pred,
                      const float* __restrict__ targ,
                      double* __restrict__ acc,
                      float w0, float w1, float w2,
                      float w3, float w4, float w5) {
    const int wid  = (blockIdx.x << 2) + (threadIdx.x >> 6);
    const int lane = threadIdx.x & 63;
    const int xt   = wid & 7;          // adjacent waves share x-halo in L1/L2
    const int yseg = (wid >> 3) & 7;
    const int pl   = wid >> 6;
    const int x    = (xt << 6) + lane;
    const int y0u  = __builtin_amdgcn_readfirstlane(yseg << 6);  // uniform

    const float* pbu = uniform_ptr(pred + (size_t)pl * (IMG_H * IMG_W));
    const float* tbu = uniform_ptr(targ + (size_t)pl * (IMG_H * IMG_W));

// Symmetric Gaussian weight by constant index (folds at compile time).
#define WSYM(M) ((M)==0||(M)==10 ? w0 : (M)==1||(M)==9 ? w1 :               \
                 (M)==2||(M)==8  ? w2 : (M)==3||(M)==7 ? w3 :               \
                 (M)==4||(M)==6  ? w4 : w5)

    // Per-lane clamped tap columns + masked weights (named scalars).
#define DECL_TAP(K)                                                          \
    const int      cq##K = x + (K) - 5;                                      \
    const unsigned co##K = (unsigned)(cq##K < 0 ? 0 :                        \
                           (cq##K > IMG_W - 1 ? IMG_W - 1 : cq##K));         \
    const float    wv##K = ((unsigned)cq##K < (unsigned)IMG_W) ? WSYM(K) : 0.f;
    DECL_TAP(0) DECL_TAP(1) DECL_TAP(2) DECL_TAP(3) DECL_TAP(4) DECL_TAP(5)
    DECL_TAP(6) DECL_TAP(7) DECL_TAP(8) DECL_TAP(9) DECL_TAP(10)
#undef DECL_TAP

    // Pixel double-buffers (A/B), 22 floats each.
#define DECL_BUF(B) float B##p0,B##p1,B##p2,B##p3,B##p4,B##p5,B##p6,B##p7,  \
                          B##p8,B##p9,B##p10,                               \
                          B##t0,B##t1,B##t2,B##t3,B##t4,B##t5,B##t6,B##t7,  \
                          B##t8,B##t9,B##t10;
    DECL_BUF(A) DECL_BUF(B)
#undef DECL_BUF

    // Shift-queue: 12 slots x 5 fields. Slots 0..9 = steady ring (oldest
    // first); 10,11 = incoming rows of the current iteration.
#define DECL_Q(F) float F##0,F##1,F##2,F##3,F##4,F##5,F##6,F##7,F##8,F##9,F##10,F##11;
    DECL_Q(rmx) DECL_Q(rmy) DECL_Q(rxx) DECL_Q(ryy) DECL_Q(rxy)
#undef DECL_Q

#define LR1(BUF, K) BUF##p##K = rp_[co##K]; BUF##t##K = rt_[co##K];
// Issue 22 loads of row (y0-5+IDX), clamped, into BUF. Base is SGPR-uniform.
#define LOADROW(BUF, IDX) do {                                               \
    const int yq_ = y0u - 5 + (IDX);                                         \
    const int yc_ = yq_ < 0 ? 0 : (yq_ > IMG_H - 1 ? IMG_H - 1 : yq_);       \
    const float* rp_ = pbu + yc_ * IMG_W;                                    \
    const float* rt_ = tbu + yc_ * IMG_W;                                    \
    LR1(BUF,0) LR1(BUF,1) LR1(BUF,2) LR1(BUF,3) LR1(BUF,4) LR1(BUF,5)        \
    LR1(BUF,6) LR1(BUF,7) LR1(BUF,8) LR1(BUF,9) LR1(BUF,10)                  \
} while (0)

#define HT(BUF, K) {                                                         \
    const float p_ = BUF##p##K, t_ = BUF##t##K;                              \
    const float wp_ = wv##K * p_, wt_ = wv##K * t_;                          \
    amx += wp_; amy += wt_;                                                  \
    axx = fmaf(wp_, p_, axx);                                                \
    ayy = fmaf(wt_, t_, ayy);                                                \
    axy = fmaf(wp_, t_, axy); }

// hconv of buffer BC (row IEXPR) into queue slot SLOT (literal).
// Out-of-image rows are select-zeroed (zero-pad conv semantics).
#define HCONV_TO(BC, SLOT, IEXPR) do {                                       \
    float amx=0.f, amy=0.f, axx=0.f, ayy=0.f, axy=0.f;                       \
    HT(BC,0) HT(BC,1) HT(BC,2) HT(BC,3) HT(BC,4) HT(BC,5)                    \
    HT(BC,6) HT(BC,7) HT(BC,8) HT(BC,9) HT(BC,10)                            \
    const bool vld_ = (unsigned)(y0u - 5 + (IEXPR)) < (unsigned)IMG_H;       \
    rmx##SLOT = vld_ ? amx : 0.f;  rmy##SLOT = vld_ ? amy : 0.f;             \
    rxx##SLOT = vld_ ? axx : 0.f;  ryy##SLOT = vld_ ? ayy : 0.f;             \
    rxy##SLOT = vld_ ? axy : 0.f;                                            \
} while (0)

// Vertical tap: weight index S (literal), queue slot Q (literal).
#define VT(S, Q) {                                                           \
    const float wk_ = WSYM(S);                                               \
    mx = fmaf(wk_, rmx##Q, mx);                                              \
    my = fmaf(wk_, rmy##Q, my);                                              \
    xx = fmaf(wk_, rxx##Q, xx);                                              \
    yy = fmaf(wk_, ryy##Q, yy);                                              \
    xy = fmaf(wk_, rxy##Q, xy); }

    const float C1 = 0.0001f;   // 0.01^2
    const float C2 = 0.0009f;   // 0.03^2
    float sum = 0.f;

#define SSIM_ACC() do {                                                      \
    const float mx2  = mx * mx, my2 = my * my;                               \
    const float mxy2 = 2.f * (mx * my);                                      \
    const float sx   = xx - mx2, sy = yy - my2;                              \
    const float sxy2 = 2.f * xy - mxy2;                                      \
    const float num  = (mxy2 + C1) * (sxy2 + C2);                            \
    const float den  = (mx2 + my2 + C1) * (sx + sy + C2);                    \
    sum += __fdividef(num, den);                                             \
} while (0)

    // ---- Prologue: rows 0..9 -> slots 0..9 (once, straight-line). ----
    LOADROW(A, 0);
#define PRO(I, BC, BN)                                                       \
    LOADROW(BN, (I)+1);                                                      \
    HCONV_TO(BC, I, I);                                                      \
    __builtin_amdgcn_sched_barrier(0x7);
    PRO(0,A,B) PRO(1,B,A) PRO(2,A,B) PRO(3,B,A) PRO(4,A,B)
    PRO(5,B,A) PRO(6,A,B) PRO(7,B,A) PRO(8,A,B) PRO(9,B,A)
#undef PRO
    // Queue now: slots 0..9 = rows 0..9; row 10 pixels staged in A.

    // ---- Main loop: i = 10,12,..,72 ; outputs j = i-10, i-9. ----
    // Body ~2.9KB -> I$-resident for all resident waves.
#pragma unroll 1
    for (int i = 10; i < 74; i += 2) {
        // Phase 1: row i (buffer A), output j=i-10 from slots 0..10.
        LOADROW(B, i + 1);
        HCONV_TO(A, 10, i);
        {
            float mx=0.f, my=0.f, xx=0.f, yy=0.f, xy=0.f;
            VT(0,0) VT(1,1) VT(2,2) VT(3,3) VT(4,4) VT(5,5)
            VT(6,6) VT(7,7) VT(8,8) VT(9,9) VT(10,10)
            SSIM_ACC();
        }
        __builtin_amdgcn_sched_barrier(0x7);
        // Phase 2: row i+1 (buffer B), output j=i-9 from slots 1..11.
        LOADROW(A, i + 2);
        HCONV_TO(B, 11, i + 1);
        {
            float mx=0.f, my=0.f, xx=0.f, yy=0.f, xy=0.f;
            VT(0,1) VT(1,2) VT(2,3) VT(3,4) VT(4,5) VT(5,6)
            VT(6,7) VT(7,8) VT(8,9) VT(9,10) VT(10,11)
            SSIM_ACC();
        }
        // Shift queue by 2 (50 v_mov).
#define SH(F) F##0=F##2; F##1=F##3; F##2=F##4; F##3=F##5; F##4=F##6;         \
              F##5=F##7; F##6=F##8; F##7=F##9; F##8=F##10; F##9=F##11;
        SH(rmx) SH(rmy) SH(rxx) SH(ryy) SH(rxy)
#undef SH
        __builtin_amdgcn_sched_barrier(0x7);
    }

#undef SSIM_ACC
#undef VT
#undef HCONV_TO
#undef HT
#undef LOADROW
#undef LR1
#undef WSYM

    // Wave tree-reduce, one f64 atomic per wave (3072 total).
#pragma unroll
    for (int m = 32; m > 0; m >>= 1) sum += __shfl_xor(sum, m);
    if (lane == 0) atomicAdd(acc, (double)sum);
}

__global__ void ssim_fin_kernel(const double* __restrict__ acc, float* __restrict__ out) {
    out[0] = (float)(1.0 - acc[0] / NPIX);
}

extern "C" void kernel_launch(void* const* d_in, const int* in_sizes, int n_in,
                              void* d_out, int out_size, void* d_ws, size_t ws_size,
                              hipStream_t stream) {
    const float* pred = (const float*)d_in[0];
    const float* targ = (const float*)d_in[1];
    float* out  = (float*)d_out;
    double* acc = (double*)d_ws;

    // Gaussian window (matches reference: exp(-(i-5)^2 / (2*1.5^2)), normalized).
    // Symmetric: w[k]==w[10-k] bit-exactly, so pass only 6 uniques.
    double g[11], s = 0.0;
    for (int i = 0; i < 11; ++i) { double d = i - 5; g[i] = exp(-(d * d) / 4.5); s += g[i]; }
    float w[6];
    for (int i = 0; i < 6; ++i) w[i] = (float)(g[i] / s);

    ssim_zero_kernel<<<1, 64, 0, stream>>>(acc);
    ssim_main_kernel<<<NTASK / 4, 256, 0, stream>>>(pred, targ, acc,
                                                    w[0], w[1], w[2], w[3], w[4], w[5]);
    ssim_fin_kernel<<<1, 1, 0, stream>>>(acc, out);
}